// Round 5
// baseline (559.683 us; speedup 1.0000x reference)
//
#include <hip/hip_runtime.h>

// SAGEConv-mean: out[n,:] = (sum_{e: dst[e]==n} x[src[e],:]) / deg[n] @ W^T + b
// N=100000, E=1000000, D=64, fp32 in/out (no fp32 MFMA -> VALU GEMM).
//
// Round 5: CSR counting-sort (fill: 74us, 70MB writeback for a 4MB payload) replaced
// by 128-node-bucket partition + LDS fp32 accumulation:
//   deg_bucket_hist: bucket sizes from node_degrees (plain stores, no atomics)
//   bucket_scan:     782-entry exclusive scan -> offs + cursor
//   partition:       bin edges, payload = src | dstl<<17 (one uint), per-block
//                    bucket reservation -> near-contiguous writes (~12MB vs 70MB)
//   xw:              y = x @ W^T -> packed bf16 (round-4 kernel, VGPR-capped)
//   bucket_gather:   block per bucket, 33KB LDS accum (pad 65), half-wave per edge:
//                    coalesced 128B bf16 row read + 2x ds_add_f32; epilogue /deg + b
// Fallback: atomic scatter + LDS GEMM (ws too small or N >= 2^17).

#define D 64
#define BSHIFT 7                  // 128 nodes per bucket
#define BNODES (1 << BSHIFT)
#define MAXB 1024                 // max buckets supported by scan/partition LDS

// Per-block edge-dtype detect: int64 little-endian => odd 32-bit words are zero
// high-halves. 64 samples -> P(false int32 hit) ~ (1/N)^64 ~ 0.
__device__ inline int detect_stride_block(const unsigned* __restrict__ words,
                                          int E, int* sflag) {
    int t = threadIdx.x;
    if (t < 64) {
        unsigned v = (t < E) ? words[2 * t + 1] : 0u;
        int any = __any(v != 0u);
        if (t == 0) *sflag = any ? 1 : 2;   // word stride: 1=int32, 2=int64
    }
    __syncthreads();
    return *sflag;
}

__device__ inline unsigned pack_bf16(float a, float b) {   // two fp32 -> bf16x2, RNE
    unsigned ua = __float_as_uint(a), ub = __float_as_uint(b);
    ua += 0x7fffu + ((ua >> 16) & 1u);
    ub += 0x7fffu + ((ub >> 16) & 1u);
    return (ua >> 16) | (ub & 0xffff0000u);
}

// ---- bucket sizes from degrees: block = 1024 nodes = 8 whole buckets ----
__global__ __launch_bounds__(256) void deg_bucket_hist(
        const float* __restrict__ deg, int* __restrict__ bcnt, int N, int nb) {
    __shared__ int lh[8];
    int t = threadIdx.x;
    if (t < 8) lh[t] = 0;
    __syncthreads();
    int n0 = blockIdx.x * 1024 + t * 4;       // 4 nodes/thread, never straddles a bucket
    int v = 0;
    #pragma unroll
    for (int j = 0; j < 4; ++j) { int n = n0 + j; if (n < N) v += (int)(deg[n] + 0.5f); }
    atomicAdd(&lh[t >> 5], v);                // LDS; 32-way same-addr, cheap
    __syncthreads();
    if (t < 8) {
        int b = blockIdx.x * 8 + t;
        if (b < nb) bcnt[b] = lh[t];          // exclusive ownership -> plain store
    }
}

// ---- exclusive scan of nb (<=1024) bucket counts, one block -------------
__global__ __launch_bounds__(256) void bucket_scan(
        const int* __restrict__ bcnt, int* __restrict__ offs,
        int* __restrict__ cursor, int nb) {
    __shared__ int s[256];
    int t = threadIdx.x;
    int c[4]; int v = 0;
    #pragma unroll
    for (int j = 0; j < 4; ++j) {
        int i = t * 4 + j;
        c[j] = (i < nb) ? bcnt[i] : 0;
        v += c[j];
    }
    int own = v;
    s[t] = v;
    __syncthreads();
    for (int off = 1; off < 256; off <<= 1) {
        int u = (t >= off) ? s[t - off] : 0;
        __syncthreads();
        s[t] += u;
        __syncthreads();
    }
    int run = s[t] - own;
    #pragma unroll
    for (int j = 0; j < 4; ++j) {
        int i = t * 4 + j;
        if (i < nb) { offs[i] = run; cursor[i] = run; run += c[j]; }
    }
}

// ---- partition: bin edges into buckets, payload src | dstl<<17 ----------
// 4096 edges/block: LDS count -> block reservation -> LDS running cursor write.
__global__ __launch_bounds__(256) void partition_kernel(
        const unsigned* __restrict__ ewords, int* __restrict__ cursor,
        unsigned* __restrict__ pairs, int E, int nb) {
    __shared__ int sflag;
    __shared__ int lhist[MAXB];
    __shared__ int lbase[MAXB];
    int s = detect_stride_block(ewords, E, &sflag);
    int t = threadIdx.x;
    for (int i = t; i < nb; i += 256) lhist[i] = 0;
    __syncthreads();

    int base = blockIdx.x * 4096;
    unsigned pv[16]; int bk[16];
    #pragma unroll
    for (int k = 0; k < 16; ++k) {
        int e = base + k * 256 + t;
        bk[k] = -1;
        if (e < E) {
            unsigned src = ewords[(size_t)e * s];
            unsigned dst = ewords[((size_t)E + e) * s];
            bk[k] = (int)(dst >> BSHIFT);
            pv[k] = src | ((dst & (BNODES - 1)) << 17);
            atomicAdd(&lhist[bk[k]], 1);
        }
    }
    __syncthreads();
    for (int hb = t; hb < nb; hb += 256) {
        int cc = lhist[hb];
        if (cc) lbase[hb] = atomicAdd(&cursor[hb], cc);
        lhist[hb] = 0;                       // reuse as running cursor
    }
    __syncthreads();
    #pragma unroll
    for (int k = 0; k < 16; ++k) {
        if (bk[k] >= 0) {
            int lpos = atomicAdd(&lhist[bk[k]], 1);
            pairs[lbase[bk[k]] + lpos] = pv[k];
        }
    }
}

// ---- y = x @ W^T -> packed bf16 (round-4, VGPR-capped) ------------------
__global__ __launch_bounds__(256, 4) void xw_kernel(
        const float* __restrict__ x, const float* __restrict__ W,
        unsigned* __restrict__ y2, int N) {
    __shared__ float Wt[64 * 68];
    __shared__ float xs[64 * 68];
    int t = threadIdx.x;
    for (int i = t; i < 64 * 64; i += 256) {
        int o = i >> 6, k = i & 63;
        Wt[k * 68 + o] = W[i];
    }
    int base = blockIdx.x * 64;
    int row = t >> 4, c4 = (t & 15) * 4;
    #pragma unroll
    for (int r = 0; r < 4; ++r) {
        int nl = row + r * 16;
        int n = base + nl;
        float4 v = {0.f, 0.f, 0.f, 0.f};
        if (n < N) v = *(const float4*)(x + (size_t)n * 64 + c4);
        *(float4*)&xs[nl * 68 + c4] = v;
    }
    __syncthreads();
    int o4 = (t & 15) * 4, nl4 = (t >> 4) * 4;
    float acc[4][4];
    #pragma unroll
    for (int i = 0; i < 4; ++i)
        #pragma unroll
        for (int j = 0; j < 4; ++j) acc[i][j] = 0.f;
    #pragma unroll 2
    for (int k0 = 0; k0 < 64; k0 += 4) {
        float a[4][4], wv[4][4];
        #pragma unroll
        for (int i = 0; i < 4; ++i)
            *(float4*)a[i] = *(const float4*)&xs[(nl4 + i) * 68 + k0];
        #pragma unroll
        for (int dk = 0; dk < 4; ++dk)
            *(float4*)wv[dk] = *(const float4*)&Wt[(k0 + dk) * 68 + o4];
        #pragma unroll
        for (int i = 0; i < 4; ++i)
            #pragma unroll
            for (int j = 0; j < 4; ++j)
                acc[i][j] += a[i][0] * wv[0][j] + a[i][1] * wv[1][j]
                           + a[i][2] * wv[2][j] + a[i][3] * wv[3][j];
    }
    int n0 = base + nl4;
    #pragma unroll
    for (int i = 0; i < 4; ++i) {
        if (n0 + i < N) {
            uint2 p;
            p.x = pack_bf16(acc[i][0], acc[i][1]);
            p.y = pack_bf16(acc[i][2], acc[i][3]);
            *(uint2*)(y2 + (size_t)(n0 + i) * 32 + (o4 >> 1)) = p;
        }
    }
}

// ---- bucket gather: LDS fp32 accum, half-wave per edge ------------------
__global__ __launch_bounds__(512) void bucket_gather(
        const unsigned* __restrict__ y2, const unsigned* __restrict__ pairs,
        const int* __restrict__ offs, const int* __restrict__ endc,
        const float* __restrict__ deg, const float* __restrict__ b,
        float* __restrict__ out, int N) {
    __shared__ float accum[BNODES * 65];     // pad 65: dstl*65 % 32 spreads banks
    int t = threadIdx.x;
    for (int i = t; i < BNODES * 65; i += 512) accum[i] = 0.f;

    int bkt = blockIdx.x;
    int nodeBase = bkt << BSHIFT;
    int start = offs[bkt], end = endc[bkt];  // endc = cursor after partition
    int lane = t & 63, wv = t >> 6;
    int h = lane >> 5, l = lane & 31;
    __syncthreads();

    for (int e0 = start + wv * 64; e0 < end; e0 += 512) {
        int m = end - e0; if (m > 64) m = 64;
        unsigned pvv = (lane < m) ? pairs[e0 + lane] : 0u;   // coalesced
        for (int j = 0; j < m; j += 2) {
            int idx = j + h;
            unsigned ep = __shfl((int)pvv, idx);
            if (idx < m) {
                unsigned src = ep & 0x1FFFFu;
                int dstl = (int)(ep >> 17);
                unsigned u = y2[(size_t)src * 32 + l];        // 128B/half-wave
                float f0 = __uint_as_float(u << 16);
                float f1 = __uint_as_float(u & 0xffff0000u);
                atomicAdd(&accum[dstl * 65 + 2 * l], f0);     // ds_add_f32
                atomicAdd(&accum[dstl * 65 + 2 * l + 1], f1);
            }
        }
    }
    __syncthreads();
    for (int i = t; i < BNODES * 64; i += 512) {
        int dstl = i >> 6, c = i & 63;
        int n = nodeBase + dstl;
        if (n < N)
            out[(size_t)n * 64 + c] = accum[dstl * 65 + c] / deg[n] + b[c];
    }
}

// ---- fallback: atomic scatter + LDS GEMM --------------------------------
__global__ __launch_bounds__(256) void scatter_kernel(
        const float* __restrict__ x, const unsigned* __restrict__ ewords,
        float* __restrict__ agg, int E) {
    __shared__ int sflag;
    int s = detect_stride_block(ewords, E, &sflag);
    int gid = blockIdx.x * blockDim.x + threadIdx.x;
    int e = gid >> 4, q = gid & 15;
    if (e >= E) return;
    int src = (int)ewords[(size_t)e * s];
    int dst = (int)ewords[((size_t)E + e) * s];
    const float4 v = *(const float4*)(x + (size_t)src * D + q * 4);
    float* p = agg + (size_t)dst * D + q * 4;
    unsafeAtomicAdd(p + 0, v.x);
    unsafeAtomicAdd(p + 1, v.y);
    unsafeAtomicAdd(p + 2, v.z);
    unsafeAtomicAdd(p + 3, v.w);
}

__global__ __launch_bounds__(256) void gemm_kernel(
        float* __restrict__ inout, const float* __restrict__ deg,
        const float* __restrict__ W, const float* __restrict__ b, int nNodes) {
    __shared__ float Wt[64 * 65];
    __shared__ float rows[4 * 64];
    int t = threadIdx.x;
    for (int i = t; i < 64 * 64; i += 256) {
        int o = i >> 6, k = i & 63;
        Wt[k * 65 + o] = W[i];
    }
    int base = blockIdx.x * 4;
    int nl = t >> 6, o = t & 63;
    int n = base + nl;
    if (n < nNodes) {
        float invd = 1.0f / deg[n];
        rows[nl * 64 + o] = inout[(size_t)n * 64 + o] * invd;
    }
    __syncthreads();
    if (n >= nNodes) return;
    float acc = b[o];
    #pragma unroll
    for (int k = 0; k < 64; ++k)
        acc += rows[nl * 64 + k] * Wt[k * 65 + o];
    inout[(size_t)n * 64 + o] = acc;
}

extern "C" void kernel_launch(void* const* d_in, const int* in_sizes, int n_in,
                              void* d_out, int out_size, void* d_ws, size_t ws_size,
                              hipStream_t stream) {
    const float*    x      = (const float*)d_in[0];
    const unsigned* ewords = (const unsigned*)d_in[1];
    const float*    deg    = (const float*)d_in[2];
    const float*    W      = (const float*)d_in[3];
    const float*    b      = (const float*)d_in[4];
    float*          out    = (float*)d_out;

    const int E = in_sizes[1] / 2;
    const int N = in_sizes[2];
    const int nb = (N + BNODES - 1) >> BSHIFT;         // 782 for N=100000

    // ws layout: bcnt[MAXB] | offs[MAXB] | cursor[MAXB] | pairs[E+N] | y2[N*32]
    char* ws = (char*)d_ws;
    size_t bcntB = MAXB * 4, offB = MAXB * 4, curB = MAXB * 4;
    size_t pairB = (((size_t)E + N) * 4 + 63) & ~63ull;
    size_t need  = bcntB + offB + curB + pairB + (size_t)N * 32 * 4;

    if (ws_size >= need && N < (1 << 17) && nb <= MAXB) {
        int*      bcnt   = (int*)ws;
        int*      offs   = (int*)(ws + bcntB);
        int*      cursor = (int*)(ws + bcntB + offB);
        unsigned* pairs  = (unsigned*)(ws + bcntB + offB + curB);
        unsigned* y2     = (unsigned*)(ws + bcntB + offB + curB + pairB);

        deg_bucket_hist<<<(N + 1023) / 1024, 256, 0, stream>>>(deg, bcnt, N, nb);
        bucket_scan<<<1, 256, 0, stream>>>(bcnt, offs, cursor, nb);
        partition_kernel<<<(E + 4095) / 4096, 256, 0, stream>>>(
            ewords, cursor, pairs, E, nb);
        xw_kernel<<<(N + 63) / 64, 256, 0, stream>>>(x, W, y2, N);
        bucket_gather<<<nb, 512, 0, stream>>>(
            y2, pairs, offs, cursor, deg, b, out, N);
    } else {
        hipMemsetAsync(d_out, 0, (size_t)out_size * sizeof(float), stream);
        long long sthreads = (long long)E * 16;
        int sblocks = (int)((sthreads + 255) / 256);
        scatter_kernel<<<sblocks, 256, 0, stream>>>(x, ewords, out, E);
        gemm_kernel<<<(N + 3) / 4, 256, 0, stream>>>(out, deg, W, b, N);
    }
}

// Round 6
// 506.126 us; speedup vs baseline: 1.1058x; 1.1058x over previous
//
#include <hip/hip_runtime.h>

// SAGEConv-mean: out[n,:] = (sum_{e: dst[e]==n} x[src[e],:]) / deg[n] @ W^T + b
// N=100000, E=1000000, D=64, fp32 in/out (no fp32 MFMA -> VALU GEMM).
//
// Round 6: fix round-5's 448us bucket_gather (fp32 LDS atomicAdd = CAS loop;
// 1 load in flight/wave). Now: unsafeAtomicAdd -> native ds_add_f32; 4 edges
// per load instruction (g=lane>>4 edge, c=lane&15 col-pair, uint2); 64-node
// buckets -> 1563 blocks x 256 thr, 16.6KB LDS -> ~full occupancy.
//   deg_bucket_hist -> bucket_scan(<=2048) -> partition(pack src|dstl<<17)
//   -> xw (y=x@W^T as packed bf16, VGPR-capped) -> bucket_gather.
// Fallback: atomic scatter + LDS GEMM (ws too small or N >= 2^17).

#define D 64
#define BSHIFT 6                  // 64 nodes per bucket
#define BNODES (1 << BSHIFT)
#define MAXB 2048                 // max buckets supported by scan/partition LDS

// Per-block edge-dtype detect: int64 little-endian => odd 32-bit words are zero
// high-halves. 64 samples -> P(false int32 hit) ~ (1/N)^64 ~ 0.
__device__ inline int detect_stride_block(const unsigned* __restrict__ words,
                                          int E, int* sflag) {
    int t = threadIdx.x;
    if (t < 64) {
        unsigned v = (t < E) ? words[2 * t + 1] : 0u;
        int any = __any(v != 0u);
        if (t == 0) *sflag = any ? 1 : 2;   // word stride: 1=int32, 2=int64
    }
    __syncthreads();
    return *sflag;
}

__device__ inline unsigned pack_bf16(float a, float b) {   // two fp32 -> bf16x2, RNE
    unsigned ua = __float_as_uint(a), ub = __float_as_uint(b);
    ua += 0x7fffu + ((ua >> 16) & 1u);
    ub += 0x7fffu + ((ub >> 16) & 1u);
    return (ua >> 16) | (ub & 0xffff0000u);
}

// ---- bucket sizes from degrees: block = 1024 nodes = 16 whole buckets ---
__global__ __launch_bounds__(256) void deg_bucket_hist(
        const float* __restrict__ deg, int* __restrict__ bcnt, int N, int nb) {
    __shared__ int lh[16];
    int t = threadIdx.x;
    if (t < 16) lh[t] = 0;
    __syncthreads();
    int n0 = blockIdx.x * 1024 + t * 4;       // 4 nodes/thread, never straddles a bucket
    int v = 0;
    #pragma unroll
    for (int j = 0; j < 4; ++j) { int n = n0 + j; if (n < N) v += (int)(deg[n] + 0.5f); }
    atomicAdd(&lh[t >> 4], v);                // LDS int atomic: native
    __syncthreads();
    if (t < 16) {
        int b = blockIdx.x * 16 + t;
        if (b < nb) bcnt[b] = lh[t];          // exclusive ownership -> plain store
    }
}

// ---- exclusive scan of nb (<=2048) bucket counts, one block -------------
__global__ __launch_bounds__(256) void bucket_scan(
        const int* __restrict__ bcnt, int* __restrict__ offs,
        int* __restrict__ cursor, int nb) {
    __shared__ int s[256];
    int t = threadIdx.x;
    int c[8]; int v = 0;
    #pragma unroll
    for (int j = 0; j < 8; ++j) {
        int i = t * 8 + j;
        c[j] = (i < nb) ? bcnt[i] : 0;
        v += c[j];
    }
    int own = v;
    s[t] = v;
    __syncthreads();
    for (int off = 1; off < 256; off <<= 1) {
        int u = (t >= off) ? s[t - off] : 0;
        __syncthreads();
        s[t] += u;
        __syncthreads();
    }
    int run = s[t] - own;
    #pragma unroll
    for (int j = 0; j < 8; ++j) {
        int i = t * 8 + j;
        if (i < nb) { offs[i] = run; cursor[i] = run; run += c[j]; }
    }
}

// ---- partition: bin edges into buckets, payload src | dstl<<17 ----------
// 4096 edges/block: LDS count -> block reservation -> LDS running cursor write.
__global__ __launch_bounds__(256) void partition_kernel(
        const unsigned* __restrict__ ewords, int* __restrict__ cursor,
        unsigned* __restrict__ pairs, int E, int nb) {
    __shared__ int sflag;
    __shared__ int lhist[MAXB];
    __shared__ int lbase[MAXB];
    int s = detect_stride_block(ewords, E, &sflag);
    int t = threadIdx.x;
    for (int i = t; i < nb; i += 256) lhist[i] = 0;
    __syncthreads();

    int base = blockIdx.x * 4096;
    unsigned pv[16]; int bk[16];
    #pragma unroll
    for (int k = 0; k < 16; ++k) {
        int e = base + k * 256 + t;
        bk[k] = -1;
        if (e < E) {
            unsigned src = ewords[(size_t)e * s];
            unsigned dst = ewords[((size_t)E + e) * s];
            bk[k] = (int)(dst >> BSHIFT);
            pv[k] = src | ((dst & (BNODES - 1)) << 17);
            atomicAdd(&lhist[bk[k]], 1);
        }
    }
    __syncthreads();
    for (int hb = t; hb < nb; hb += 256) {
        int cc = lhist[hb];
        if (cc) lbase[hb] = atomicAdd(&cursor[hb], cc);
        lhist[hb] = 0;                       // reuse as running cursor
    }
    __syncthreads();
    #pragma unroll
    for (int k = 0; k < 16; ++k) {
        if (bk[k] >= 0) {
            int lpos = atomicAdd(&lhist[bk[k]], 1);
            pairs[lbase[bk[k]] + lpos] = pv[k];
        }
    }
}

// ---- y = x @ W^T -> packed bf16 (round-4, VGPR-capped) ------------------
__global__ __launch_bounds__(256, 4) void xw_kernel(
        const float* __restrict__ x, const float* __restrict__ W,
        unsigned* __restrict__ y2, int N) {
    __shared__ float Wt[64 * 68];
    __shared__ float xs[64 * 68];
    int t = threadIdx.x;
    for (int i = t; i < 64 * 64; i += 256) {
        int o = i >> 6, k = i & 63;
        Wt[k * 68 + o] = W[i];
    }
    int base = blockIdx.x * 64;
    int row = t >> 4, c4 = (t & 15) * 4;
    #pragma unroll
    for (int r = 0; r < 4; ++r) {
        int nl = row + r * 16;
        int n = base + nl;
        float4 v = {0.f, 0.f, 0.f, 0.f};
        if (n < N) v = *(const float4*)(x + (size_t)n * 64 + c4);
        *(float4*)&xs[nl * 68 + c4] = v;
    }
    __syncthreads();
    int o4 = (t & 15) * 4, nl4 = (t >> 4) * 4;
    float acc[4][4];
    #pragma unroll
    for (int i = 0; i < 4; ++i)
        #pragma unroll
        for (int j = 0; j < 4; ++j) acc[i][j] = 0.f;
    #pragma unroll 2
    for (int k0 = 0; k0 < 64; k0 += 4) {
        float a[4][4], wv[4][4];
        #pragma unroll
        for (int i = 0; i < 4; ++i)
            *(float4*)a[i] = *(const float4*)&xs[(nl4 + i) * 68 + k0];
        #pragma unroll
        for (int dk = 0; dk < 4; ++dk)
            *(float4*)wv[dk] = *(const float4*)&Wt[(k0 + dk) * 68 + o4];
        #pragma unroll
        for (int i = 0; i < 4; ++i)
            #pragma unroll
            for (int j = 0; j < 4; ++j)
                acc[i][j] += a[i][0] * wv[0][j] + a[i][1] * wv[1][j]
                           + a[i][2] * wv[2][j] + a[i][3] * wv[3][j];
    }
    int n0 = base + nl4;
    #pragma unroll
    for (int i = 0; i < 4; ++i) {
        if (n0 + i < N) {
            uint2 p;
            p.x = pack_bf16(acc[i][0], acc[i][1]);
            p.y = pack_bf16(acc[i][2], acc[i][3]);
            *(uint2*)(y2 + (size_t)(n0 + i) * 32 + (o4 >> 1)) = p;
        }
    }
}

// ---- bucket gather: native ds_add_f32 accum, 4 edges per load instr -----
__global__ __launch_bounds__(256) void bucket_gather(
        const unsigned* __restrict__ y2, const unsigned* __restrict__ pairs,
        const int* __restrict__ offs, const int* __restrict__ endc,
        const float* __restrict__ deg, const float* __restrict__ b,
        float* __restrict__ out, int N) {
    __shared__ float accum[BNODES * 65];     // 16.6 KB; bank = (dstl + 4c) % 32
    int t = threadIdx.x;
    for (int i = t; i < BNODES * 65; i += 256) accum[i] = 0.f;

    int bkt = blockIdx.x;
    int nodeBase = bkt << BSHIFT;
    int start = offs[bkt], end = endc[bkt];  // endc = cursor after partition
    int lane = t & 63, wv = t >> 6;
    int g = lane >> 4, c = lane & 15;        // edge group / column pair-group
    __syncthreads();

    for (int e0 = start + wv * 64; e0 < end; e0 += 256) {
        int m = end - e0; if (m > 64) m = 64;
        unsigned pvv = (lane < m) ? pairs[e0 + lane] : 0u;   // coalesced
        #pragma unroll 4                      // >=4 uint2 loads in flight
        for (int j = 0; j < m; j += 4) {
            int idx = j + g;
            unsigned ep = __shfl((int)pvv, idx);
            if (idx < m) {
                unsigned src = ep & 0x1FFFFu;
                int dstl = (int)(ep >> 17);
                uint2 u = *(const uint2*)(y2 + (size_t)src * 32 + c * 2); // 4 rows/instr
                float* a = &accum[dstl * 65 + c * 4];
                unsafeAtomicAdd(a + 0, __uint_as_float(u.x << 16));       // ds_add_f32
                unsafeAtomicAdd(a + 1, __uint_as_float(u.x & 0xffff0000u));
                unsafeAtomicAdd(a + 2, __uint_as_float(u.y << 16));
                unsafeAtomicAdd(a + 3, __uint_as_float(u.y & 0xffff0000u));
            }
        }
    }
    __syncthreads();
    for (int i = t; i < BNODES * 16; i += 256) {     // float4 epilogue
        int dstl = i >> 4, c4 = (i & 15) * 4;
        int n = nodeBase + dstl;
        if (n < N) {
            float invd = 1.0f / deg[n];
            const float* a = &accum[dstl * 65 + c4];
            float4 o4v = {a[0] * invd + b[c4 + 0], a[1] * invd + b[c4 + 1],
                          a[2] * invd + b[c4 + 2], a[3] * invd + b[c4 + 3]};
            *(float4*)(out + (size_t)n * 64 + c4) = o4v;
        }
    }
}

// ---- fallback: atomic scatter + LDS GEMM --------------------------------
__global__ __launch_bounds__(256) void scatter_kernel(
        const float* __restrict__ x, const unsigned* __restrict__ ewords,
        float* __restrict__ agg, int E) {
    __shared__ int sflag;
    int s = detect_stride_block(ewords, E, &sflag);
    int gid = blockIdx.x * blockDim.x + threadIdx.x;
    int e = gid >> 4, q = gid & 15;
    if (e >= E) return;
    int src = (int)ewords[(size_t)e * s];
    int dst = (int)ewords[((size_t)E + e) * s];
    const float4 v = *(const float4*)(x + (size_t)src * D + q * 4);
    float* p = agg + (size_t)dst * D + q * 4;
    unsafeAtomicAdd(p + 0, v.x);
    unsafeAtomicAdd(p + 1, v.y);
    unsafeAtomicAdd(p + 2, v.z);
    unsafeAtomicAdd(p + 3, v.w);
}

__global__ __launch_bounds__(256) void gemm_kernel(
        float* __restrict__ inout, const float* __restrict__ deg,
        const float* __restrict__ W, const float* __restrict__ b, int nNodes) {
    __shared__ float Wt[64 * 65];
    __shared__ float rows[4 * 64];
    int t = threadIdx.x;
    for (int i = t; i < 64 * 64; i += 256) {
        int o = i >> 6, k = i & 63;
        Wt[k * 65 + o] = W[i];
    }
    int base = blockIdx.x * 4;
    int nl = t >> 6, o = t & 63;
    int n = base + nl;
    if (n < nNodes) {
        float invd = 1.0f / deg[n];
        rows[nl * 64 + o] = inout[(size_t)n * 64 + o] * invd;
    }
    __syncthreads();
    if (n >= nNodes) return;
    float acc = b[o];
    #pragma unroll
    for (int k = 0; k < 64; ++k)
        acc += rows[nl * 64 + k] * Wt[k * 65 + o];
    inout[(size_t)n * 64 + o] = acc;
}

extern "C" void kernel_launch(void* const* d_in, const int* in_sizes, int n_in,
                              void* d_out, int out_size, void* d_ws, size_t ws_size,
                              hipStream_t stream) {
    const float*    x      = (const float*)d_in[0];
    const unsigned* ewords = (const unsigned*)d_in[1];
    const float*    deg    = (const float*)d_in[2];
    const float*    W      = (const float*)d_in[3];
    const float*    b      = (const float*)d_in[4];
    float*          out    = (float*)d_out;

    const int E = in_sizes[1] / 2;
    const int N = in_sizes[2];
    const int nb = (N + BNODES - 1) >> BSHIFT;         // 1563 for N=100000

    // ws layout: bcnt[MAXB] | offs[MAXB] | cursor[MAXB] | pairs[E+N] | y2[N*32]
    char* ws = (char*)d_ws;
    size_t bcntB = MAXB * 4, offB = MAXB * 4, curB = MAXB * 4;
    size_t pairB = (((size_t)E + N) * 4 + 63) & ~63ull;
    size_t need  = bcntB + offB + curB + pairB + (size_t)N * 32 * 4;

    if (ws_size >= need && N < (1 << 17) && nb <= MAXB) {
        int*      bcnt   = (int*)ws;
        int*      offs   = (int*)(ws + bcntB);
        int*      cursor = (int*)(ws + bcntB + offB);
        unsigned* pairs  = (unsigned*)(ws + bcntB + offB + curB);
        unsigned* y2     = (unsigned*)(ws + bcntB + offB + curB + pairB);

        deg_bucket_hist<<<(N + 1023) / 1024, 256, 0, stream>>>(deg, bcnt, N, nb);
        bucket_scan<<<1, 256, 0, stream>>>(bcnt, offs, cursor, nb);
        partition_kernel<<<(E + 4095) / 4096, 256, 0, stream>>>(
            ewords, cursor, pairs, E, nb);
        xw_kernel<<<(N + 63) / 64, 256, 0, stream>>>(x, W, y2, N);
        bucket_gather<<<nb, 256, 0, stream>>>(
            y2, pairs, offs, cursor, deg, b, out, N);
    } else {
        hipMemsetAsync(d_out, 0, (size_t)out_size * sizeof(float), stream);
        long long sthreads = (long long)E * 16;
        int sblocks = (int)((sthreads + 255) / 256);
        scatter_kernel<<<sblocks, 256, 0, stream>>>(x, ewords, out, E);
        gemm_kernel<<<(N + 3) / 4, 256, 0, stream>>>(out, deg, W, b, N);
    }
}

// Round 7
// 181.281 us; speedup vs baseline: 3.0874x; 2.7919x over previous
//
#include <hip/hip_runtime.h>

// SAGEConv-mean: out[n,:] = (sum_{e: dst[e]==n} x[src[e],:]) / deg[n] @ W^T + b
// N=100000, E=1000000, D=64, fp32 in/out (no fp32 MFMA -> VALU GEMM).
//
// Round 7: r5/r6's 400us bucket_gather was killed by per-edge LDS float atomics
// (generic-pointer unsafeAtomicAdd -> flat atomic; vmcnt(0) before every group ->
// ~1 load in flight). Now atomic-free gather:
//   partition (8192 edges/block, 2 sub-batches) -> pairs bucketed by 128-node dst
//   bucket_gather: per block, counting-sort the bucket's edges in LDS (int LDS
//     atomics on 128 counters only), then each 16-lane group owns one node and
//     register-accumulates its bf16 y2 rows; /deg + b -> out. No float atomics,
//     no shfl in the hot loop; one uint2 load instr covers 4 nodes.
//   xw: y = x @ W^T -> packed bf16 (VGPR-capped, unchanged).
// Fallback: atomic scatter + LDS GEMM (ws too small or N >= 2^17).

#define D 64
#define BSHIFT 7                  // 128 nodes per bucket
#define BNODES (1 << BSHIFT)
#define CAP 2048                  // edges staged in LDS per chunk (mean 1280)
#define MAXB 2048                 // max buckets supported by scan/partition LDS

// Per-block edge-dtype detect: int64 little-endian => odd 32-bit words are zero
// high-halves. 64 samples -> P(false int32 hit) ~ (1/N)^64 ~ 0.
__device__ inline int detect_stride_block(const unsigned* __restrict__ words,
                                          int E, int* sflag) {
    int t = threadIdx.x;
    if (t < 64) {
        unsigned v = (t < E) ? words[2 * t + 1] : 0u;
        int any = __any(v != 0u);
        if (t == 0) *sflag = any ? 1 : 2;   // word stride: 1=int32, 2=int64
    }
    __syncthreads();
    return *sflag;
}

__device__ inline unsigned pack_bf16(float a, float b) {   // two fp32 -> bf16x2, RNE
    unsigned ua = __float_as_uint(a), ub = __float_as_uint(b);
    ua += 0x7fffu + ((ua >> 16) & 1u);
    ub += 0x7fffu + ((ub >> 16) & 1u);
    return (ua >> 16) | (ub & 0xffff0000u);
}

// ---- bucket sizes from degrees: block = 1024 nodes = 8 whole buckets ----
__global__ __launch_bounds__(256) void deg_bucket_hist(
        const float* __restrict__ deg, int* __restrict__ bcnt, int N, int nb) {
    __shared__ int lh[8];
    int t = threadIdx.x;
    if (t < 8) lh[t] = 0;
    __syncthreads();
    int n0 = blockIdx.x * 1024 + t * 4;       // 4 nodes/thread, never straddles a bucket
    int v = 0;
    #pragma unroll
    for (int j = 0; j < 4; ++j) { int n = n0 + j; if (n < N) v += (int)(deg[n] + 0.5f); }
    atomicAdd(&lh[t >> 5], v);                // LDS int atomic: native
    __syncthreads();
    if (t < 8) {
        int b = blockIdx.x * 8 + t;
        if (b < nb) bcnt[b] = lh[t];          // exclusive ownership -> plain store
    }
}

// ---- exclusive scan of nb (<=2048) bucket counts, one block -------------
__global__ __launch_bounds__(256) void bucket_scan(
        const int* __restrict__ bcnt, int* __restrict__ offs,
        int* __restrict__ cursor, int nb) {
    __shared__ int s[256];
    int t = threadIdx.x;
    int c[8]; int v = 0;
    #pragma unroll
    for (int j = 0; j < 8; ++j) {
        int i = t * 8 + j;
        c[j] = (i < nb) ? bcnt[i] : 0;
        v += c[j];
    }
    int own = v;
    s[t] = v;
    __syncthreads();
    for (int off = 1; off < 256; off <<= 1) {
        int u = (t >= off) ? s[t - off] : 0;
        __syncthreads();
        s[t] += u;
        __syncthreads();
    }
    int run = s[t] - own;
    #pragma unroll
    for (int j = 0; j < 8; ++j) {
        int i = t * 8 + j;
        if (i < nb) { offs[i] = run; cursor[i] = run; run += c[j]; }
    }
}

// ---- partition: bin edges into buckets, payload src | dstl<<17 ----------
// 8192 edges/block (2 sub-batches of 4096): LDS count -> block reservation ->
// LDS running-cursor write. Longer per-bucket runs -> less writeback.
__global__ __launch_bounds__(256) void partition_kernel(
        const unsigned* __restrict__ ewords, int* __restrict__ cursor,
        unsigned* __restrict__ pairs, int E, int nb) {
    __shared__ int sflag;
    __shared__ int lhist[MAXB];
    __shared__ int lbase[MAXB];
    int s = detect_stride_block(ewords, E, &sflag);
    int t = threadIdx.x;
    for (int sub = 0; sub < 2; ++sub) {
        int base = blockIdx.x * 8192 + sub * 4096;
        if (base >= E) break;                 // uniform across block
        for (int i = t; i < nb; i += 256) lhist[i] = 0;
        __syncthreads();
        unsigned pv[16]; int bk[16];
        #pragma unroll
        for (int k = 0; k < 16; ++k) {
            int e = base + k * 256 + t;
            bk[k] = -1;
            if (e < E) {
                unsigned src = ewords[(size_t)e * s];
                unsigned dst = ewords[((size_t)E + e) * s];
                bk[k] = (int)(dst >> BSHIFT);
                pv[k] = src | ((dst & (BNODES - 1)) << 17);
                atomicAdd(&lhist[bk[k]], 1);
            }
        }
        __syncthreads();
        for (int hb = t; hb < nb; hb += 256) {
            int cc = lhist[hb];
            if (cc) lbase[hb] = atomicAdd(&cursor[hb], cc);
            lhist[hb] = 0;                    // reuse as running cursor
        }
        __syncthreads();
        #pragma unroll
        for (int k = 0; k < 16; ++k) {
            if (bk[k] >= 0) {
                int lpos = atomicAdd(&lhist[bk[k]], 1);
                pairs[lbase[bk[k]] + lpos] = pv[k];
            }
        }
        __syncthreads();                      // protect lhist/lbase for next sub
    }
}

// ---- y = x @ W^T -> packed bf16 (VGPR-capped) ---------------------------
__global__ __launch_bounds__(256, 4) void xw_kernel(
        const float* __restrict__ x, const float* __restrict__ W,
        unsigned* __restrict__ y2, int N) {
    __shared__ float Wt[64 * 68];
    __shared__ float xs[64 * 68];
    int t = threadIdx.x;
    for (int i = t; i < 64 * 64; i += 256) {
        int o = i >> 6, k = i & 63;
        Wt[k * 68 + o] = W[i];
    }
    int base = blockIdx.x * 64;
    int row = t >> 4, c4 = (t & 15) * 4;
    #pragma unroll
    for (int r = 0; r < 4; ++r) {
        int nl = row + r * 16;
        int n = base + nl;
        float4 v = {0.f, 0.f, 0.f, 0.f};
        if (n < N) v = *(const float4*)(x + (size_t)n * 64 + c4);
        *(float4*)&xs[nl * 68 + c4] = v;
    }
    __syncthreads();
    int o4 = (t & 15) * 4, nl4 = (t >> 4) * 4;
    float acc[4][4];
    #pragma unroll
    for (int i = 0; i < 4; ++i)
        #pragma unroll
        for (int j = 0; j < 4; ++j) acc[i][j] = 0.f;
    #pragma unroll 2
    for (int k0 = 0; k0 < 64; k0 += 4) {
        float a[4][4], wv[4][4];
        #pragma unroll
        for (int i = 0; i < 4; ++i)
            *(float4*)a[i] = *(const float4*)&xs[(nl4 + i) * 68 + k0];
        #pragma unroll
        for (int dk = 0; dk < 4; ++dk)
            *(float4*)wv[dk] = *(const float4*)&Wt[(k0 + dk) * 68 + o4];
        #pragma unroll
        for (int i = 0; i < 4; ++i)
            #pragma unroll
            for (int j = 0; j < 4; ++j)
                acc[i][j] += a[i][0] * wv[0][j] + a[i][1] * wv[1][j]
                           + a[i][2] * wv[2][j] + a[i][3] * wv[3][j];
    }
    int n0 = base + nl4;
    #pragma unroll
    for (int i = 0; i < 4; ++i) {
        if (n0 + i < N) {
            uint2 p;
            p.x = pack_bf16(acc[i][0], acc[i][1]);
            p.y = pack_bf16(acc[i][2], acc[i][3]);
            *(uint2*)(y2 + (size_t)(n0 + i) * 32 + (o4 >> 1)) = p;
        }
    }
}

// ---- bucket gather: LDS counting-sort + per-node register accumulation --
__global__ __launch_bounds__(256) void bucket_gather(
        const unsigned* __restrict__ y2, const unsigned* __restrict__ pairs,
        const int* __restrict__ offs, const int* __restrict__ endc,
        const float* __restrict__ deg, const float* __restrict__ b,
        float* __restrict__ out, int N) {
    __shared__ unsigned list[CAP];           // sorted srcs, 8 KB
    __shared__ int cnt[BNODES], st[BNODES], sc[BNODES];
    int t = threadIdx.x;
    int bkt = blockIdx.x, base = bkt << BSHIFT;
    int start = offs[bkt], end = endc[bkt];  // endc = cursor after partition
    int lane = t & 63, w = t >> 6;
    int g = lane >> 4, c = lane & 15;        // node sub-index / column quad
    float4 bv = ((const float4*)b)[c];
    int nchunk = (end - start + CAP - 1) / CAP;
    if (nchunk < 1) nchunk = 1;              // empty bucket: still write b

    for (int ci = 0; ci < nchunk; ++ci) {
        int e0 = start + ci * CAP;
        int cn = end - e0; if (cn > CAP) cn = CAP; if (cn < 0) cn = 0;
        for (int i = t; i < BNODES; i += 256) cnt[i] = 0;
        __syncthreads();
        for (int i = t; i < cn; i += 256)                 // histogram (int LDS atomic)
            atomicAdd(&cnt[pairs[e0 + i] >> 17], 1);
        __syncthreads();
        if (t < BNODES) sc[t] = cnt[t];
        __syncthreads();
        for (int off = 1; off < BNODES; off <<= 1) {      // inclusive scan
            int v = (t < BNODES && t >= off) ? sc[t - off] : 0;
            __syncthreads();
            if (t < BNODES) sc[t] += v;
            __syncthreads();
        }
        if (t < BNODES) { st[t] = sc[t] - cnt[t]; sc[t] = sc[t] - cnt[t]; }
        __syncthreads();
        for (int i = t; i < cn; i += 256) {               // scatter (sort by dstl)
            unsigned p = pairs[e0 + i];                   // L2-resident re-read
            int pos = atomicAdd(&sc[p >> 17], 1);
            list[pos] = p & 0x1FFFFu;                     // src only
        }
        __syncthreads();

        // gather: wave w owns nodes [w*32, w*32+32); 4 nodes per step via g
        for (int nl0 = w * 32; nl0 < w * 32 + 32; nl0 += 4) {
            int mynode = nl0 + g;
            int n = base + mynode;
            int s0 = st[mynode], e1 = s0 + cnt[mynode];
            float ax = 0.f, ay = 0.f, az = 0.f, aw = 0.f;
            for (int i = s0; i < e1; ++i) {               // group-divergent trip
                unsigned src = list[i];                   // broadcast within group
                uint2 u = *(const uint2*)(y2 + (size_t)src * 32 + c * 2);
                ax += __uint_as_float(u.x << 16);
                ay += __uint_as_float(u.x & 0xffff0000u);
                az += __uint_as_float(u.y << 16);
                aw += __uint_as_float(u.y & 0xffff0000u);
            }
            if (n < N) {
                float* op = out + (size_t)n * 64 + c * 4;
                if (nchunk == 1) {
                    float invd = 1.0f / deg[n];
                    float4 o4 = {ax * invd + bv.x, ay * invd + bv.y,
                                 az * invd + bv.z, aw * invd + bv.w};
                    *(float4*)op = o4;
                } else {                                  // rare multi-chunk path
                    float4 p = {0.f, 0.f, 0.f, 0.f};
                    if (ci > 0) p = *(const float4*)op;   // same thread wrote it
                    p.x += ax; p.y += ay; p.z += az; p.w += aw;
                    if (ci == nchunk - 1) {
                        float invd = 1.0f / deg[n];
                        p = {p.x * invd + bv.x, p.y * invd + bv.y,
                             p.z * invd + bv.z, p.w * invd + bv.w};
                    }
                    *(float4*)op = p;
                }
            }
        }
        __syncthreads();                                  // LDS reuse next chunk
    }
}

// ---- fallback: atomic scatter + LDS GEMM --------------------------------
__global__ __launch_bounds__(256) void scatter_kernel(
        const float* __restrict__ x, const unsigned* __restrict__ ewords,
        float* __restrict__ agg, int E) {
    __shared__ int sflag;
    int s = detect_stride_block(ewords, E, &sflag);
    int gid = blockIdx.x * blockDim.x + threadIdx.x;
    int e = gid >> 4, q = gid & 15;
    if (e >= E) return;
    int src = (int)ewords[(size_t)e * s];
    int dst = (int)ewords[((size_t)E + e) * s];
    const float4 v = *(const float4*)(x + (size_t)src * D + q * 4);
    float* p = agg + (size_t)dst * D + q * 4;
    unsafeAtomicAdd(p + 0, v.x);
    unsafeAtomicAdd(p + 1, v.y);
    unsafeAtomicAdd(p + 2, v.z);
    unsafeAtomicAdd(p + 3, v.w);
}

__global__ __launch_bounds__(256) void gemm_kernel(
        float* __restrict__ inout, const float* __restrict__ deg,
        const float* __restrict__ W, const float* __restrict__ b, int nNodes) {
    __shared__ float Wt[64 * 65];
    __shared__ float rows[4 * 64];
    int t = threadIdx.x;
    for (int i = t; i < 64 * 64; i += 256) {
        int o = i >> 6, k = i & 63;
        Wt[k * 65 + o] = W[i];
    }
    int base = blockIdx.x * 4;
    int nl = t >> 6, o = t & 63;
    int n = base + nl;
    if (n < nNodes) {
        float invd = 1.0f / deg[n];
        rows[nl * 64 + o] = inout[(size_t)n * 64 + o] * invd;
    }
    __syncthreads();
    if (n >= nNodes) return;
    float acc = b[o];
    #pragma unroll
    for (int k = 0; k < 64; ++k)
        acc += rows[nl * 64 + k] * Wt[k * 65 + o];
    inout[(size_t)n * 64 + o] = acc;
}

extern "C" void kernel_launch(void* const* d_in, const int* in_sizes, int n_in,
                              void* d_out, int out_size, void* d_ws, size_t ws_size,
                              hipStream_t stream) {
    const float*    x      = (const float*)d_in[0];
    const unsigned* ewords = (const unsigned*)d_in[1];
    const float*    deg    = (const float*)d_in[2];
    const float*    W      = (const float*)d_in[3];
    const float*    b      = (const float*)d_in[4];
    float*          out    = (float*)d_out;

    const int E = in_sizes[1] / 2;
    const int N = in_sizes[2];
    const int nb = (N + BNODES - 1) >> BSHIFT;         // 782 for N=100000

    // ws layout: bcnt[MAXB] | offs[MAXB] | cursor[MAXB] | pairs[E+N] | y2[N*32]
    char* ws = (char*)d_ws;
    size_t bcntB = MAXB * 4, offB = MAXB * 4, curB = MAXB * 4;
    size_t pairB = (((size_t)E + N) * 4 + 63) & ~63ull;
    size_t need  = bcntB + offB + curB + pairB + (size_t)N * 32 * 4;

    if (ws_size >= need && N < (1 << 17) && nb <= MAXB) {
        int*      bcnt   = (int*)ws;
        int*      offs   = (int*)(ws + bcntB);
        int*      cursor = (int*)(ws + bcntB + offB);
        unsigned* pairs  = (unsigned*)(ws + bcntB + offB + curB);
        unsigned* y2     = (unsigned*)(ws + bcntB + offB + curB + pairB);

        deg_bucket_hist<<<(N + 1023) / 1024, 256, 0, stream>>>(deg, bcnt, N, nb);
        bucket_scan<<<1, 256, 0, stream>>>(bcnt, offs, cursor, nb);
        partition_kernel<<<(E + 8191) / 8192, 256, 0, stream>>>(
            ewords, cursor, pairs, E, nb);
        xw_kernel<<<(N + 63) / 64, 256, 0, stream>>>(x, W, y2, N);
        bucket_gather<<<nb, 256, 0, stream>>>(
            y2, pairs, offs, cursor, deg, b, out, N);
    } else {
        hipMemsetAsync(d_out, 0, (size_t)out_size * sizeof(float), stream);
        long long sthreads = (long long)E * 16;
        int sblocks = (int)((sthreads + 255) / 256);
        scatter_kernel<<<sblocks, 256, 0, stream>>>(x, ewords, out, E);
        gemm_kernel<<<(N + 3) / 4, 256, 0, stream>>>(out, deg, W, b, N);
    }
}

// Round 8
// 161.641 us; speedup vs baseline: 3.4625x; 1.1215x over previous
//
#include <hip/hip_runtime.h>

// SAGEConv-mean: out[n,:] = (sum_{e: dst[e]==n} x[src[e],:]) / deg[n] @ W^T + b
// N=100000, E=1000000, D=64, fp32 in/out (no fp32 MFMA -> VALU GEMM).
//
// Round 8: r7's gather was occupancy-capped (782 blocks x 4 waves = 38% ceiling,
// measured 27%). Now 512 threads/block (8 waves) -> 76% ceiling, same 128-node
// buckets (partition write-runs unchanged); bucket pairs register-staged (one
// coalesced read, hist/scan/scatter from registers).
//   deg_bucket_hist -> bucket_scan -> partition(8192/blk) -> xw(bf16 y) ->
//   bucket_gather(LDS counting-sort + per-node register accumulation).
// Fallback: atomic scatter + LDS GEMM (ws too small or N >= 2^17).

#define D 64
#define BSHIFT 7                  // 128 nodes per bucket
#define BNODES (1 << BSHIFT)
#define CAP 2048                  // edges staged in LDS per chunk (mean 1280)
#define GTHREADS 512
#define PERTHREAD (CAP / GTHREADS)   // 4
#define MAXB 2048                 // max buckets supported by scan/partition LDS

// Per-block edge-dtype detect: int64 little-endian => odd 32-bit words are zero
// high-halves. 64 samples -> P(false int32 hit) ~ (1/N)^64 ~ 0.
__device__ inline int detect_stride_block(const unsigned* __restrict__ words,
                                          int E, int* sflag) {
    int t = threadIdx.x;
    if (t < 64) {
        unsigned v = (t < E) ? words[2 * t + 1] : 0u;
        int any = __any(v != 0u);
        if (t == 0) *sflag = any ? 1 : 2;   // word stride: 1=int32, 2=int64
    }
    __syncthreads();
    return *sflag;
}

__device__ inline unsigned pack_bf16(float a, float b) {   // two fp32 -> bf16x2, RNE
    unsigned ua = __float_as_uint(a), ub = __float_as_uint(b);
    ua += 0x7fffu + ((ua >> 16) & 1u);
    ub += 0x7fffu + ((ub >> 16) & 1u);
    return (ua >> 16) | (ub & 0xffff0000u);
}

// ---- bucket sizes from degrees: block = 1024 nodes = 8 whole buckets ----
__global__ __launch_bounds__(256) void deg_bucket_hist(
        const float* __restrict__ deg, int* __restrict__ bcnt, int N, int nb) {
    __shared__ int lh[8];
    int t = threadIdx.x;
    if (t < 8) lh[t] = 0;
    __syncthreads();
    int n0 = blockIdx.x * 1024 + t * 4;       // 4 nodes/thread, never straddles a bucket
    int v = 0;
    #pragma unroll
    for (int j = 0; j < 4; ++j) { int n = n0 + j; if (n < N) v += (int)(deg[n] + 0.5f); }
    atomicAdd(&lh[t >> 5], v);                // LDS int atomic: native
    __syncthreads();
    if (t < 8) {
        int b = blockIdx.x * 8 + t;
        if (b < nb) bcnt[b] = lh[t];          // exclusive ownership -> plain store
    }
}

// ---- exclusive scan of nb (<=2048) bucket counts, one block -------------
__global__ __launch_bounds__(256) void bucket_scan(
        const int* __restrict__ bcnt, int* __restrict__ offs,
        int* __restrict__ cursor, int nb) {
    __shared__ int s[256];
    int t = threadIdx.x;
    int c[8]; int v = 0;
    #pragma unroll
    for (int j = 0; j < 8; ++j) {
        int i = t * 8 + j;
        c[j] = (i < nb) ? bcnt[i] : 0;
        v += c[j];
    }
    int own = v;
    s[t] = v;
    __syncthreads();
    for (int off = 1; off < 256; off <<= 1) {
        int u = (t >= off) ? s[t - off] : 0;
        __syncthreads();
        s[t] += u;
        __syncthreads();
    }
    int run = s[t] - own;
    #pragma unroll
    for (int j = 0; j < 8; ++j) {
        int i = t * 8 + j;
        if (i < nb) { offs[i] = run; cursor[i] = run; run += c[j]; }
    }
}

// ---- partition: bin edges into buckets, payload src | dstl<<17 ----------
// 8192 edges/block (2 sub-batches of 4096): LDS count -> block reservation ->
// LDS running-cursor write.
__global__ __launch_bounds__(256) void partition_kernel(
        const unsigned* __restrict__ ewords, int* __restrict__ cursor,
        unsigned* __restrict__ pairs, int E, int nb) {
    __shared__ int sflag;
    __shared__ int lhist[MAXB];
    __shared__ int lbase[MAXB];
    int s = detect_stride_block(ewords, E, &sflag);
    int t = threadIdx.x;
    for (int sub = 0; sub < 2; ++sub) {
        int base = blockIdx.x * 8192 + sub * 4096;
        if (base >= E) break;                 // uniform across block
        for (int i = t; i < nb; i += 256) lhist[i] = 0;
        __syncthreads();
        unsigned pv[16]; int bk[16];
        #pragma unroll
        for (int k = 0; k < 16; ++k) {
            int e = base + k * 256 + t;
            bk[k] = -1;
            if (e < E) {
                unsigned src = ewords[(size_t)e * s];
                unsigned dst = ewords[((size_t)E + e) * s];
                bk[k] = (int)(dst >> BSHIFT);
                pv[k] = src | ((dst & (BNODES - 1)) << 17);
                atomicAdd(&lhist[bk[k]], 1);
            }
        }
        __syncthreads();
        for (int hb = t; hb < nb; hb += 256) {
            int cc = lhist[hb];
            if (cc) lbase[hb] = atomicAdd(&cursor[hb], cc);
            lhist[hb] = 0;                    // reuse as running cursor
        }
        __syncthreads();
        #pragma unroll
        for (int k = 0; k < 16; ++k) {
            if (bk[k] >= 0) {
                int lpos = atomicAdd(&lhist[bk[k]], 1);
                pairs[lbase[bk[k]] + lpos] = pv[k];
            }
        }
        __syncthreads();                      // protect lhist/lbase for next sub
    }
}

// ---- y = x @ W^T -> packed bf16 (VGPR-capped) ---------------------------
__global__ __launch_bounds__(256, 4) void xw_kernel(
        const float* __restrict__ x, const float* __restrict__ W,
        unsigned* __restrict__ y2, int N) {
    __shared__ float Wt[64 * 68];
    __shared__ float xs[64 * 68];
    int t = threadIdx.x;
    for (int i = t; i < 64 * 64; i += 256) {
        int o = i >> 6, k = i & 63;
        Wt[k * 68 + o] = W[i];
    }
    int base = blockIdx.x * 64;
    int row = t >> 4, c4 = (t & 15) * 4;
    #pragma unroll
    for (int r = 0; r < 4; ++r) {
        int nl = row + r * 16;
        int n = base + nl;
        float4 v = {0.f, 0.f, 0.f, 0.f};
        if (n < N) v = *(const float4*)(x + (size_t)n * 64 + c4);
        *(float4*)&xs[nl * 68 + c4] = v;
    }
    __syncthreads();
    int o4 = (t & 15) * 4, nl4 = (t >> 4) * 4;
    float acc[4][4];
    #pragma unroll
    for (int i = 0; i < 4; ++i)
        #pragma unroll
        for (int j = 0; j < 4; ++j) acc[i][j] = 0.f;
    #pragma unroll 2
    for (int k0 = 0; k0 < 64; k0 += 4) {
        float a[4][4], wv[4][4];
        #pragma unroll
        for (int i = 0; i < 4; ++i)
            *(float4*)a[i] = *(const float4*)&xs[(nl4 + i) * 68 + k0];
        #pragma unroll
        for (int dk = 0; dk < 4; ++dk)
            *(float4*)wv[dk] = *(const float4*)&Wt[(k0 + dk) * 68 + o4];
        #pragma unroll
        for (int i = 0; i < 4; ++i)
            #pragma unroll
            for (int j = 0; j < 4; ++j)
                acc[i][j] += a[i][0] * wv[0][j] + a[i][1] * wv[1][j]
                           + a[i][2] * wv[2][j] + a[i][3] * wv[3][j];
    }
    int n0 = base + nl4;
    #pragma unroll
    for (int i = 0; i < 4; ++i) {
        if (n0 + i < N) {
            uint2 p;
            p.x = pack_bf16(acc[i][0], acc[i][1]);
            p.y = pack_bf16(acc[i][2], acc[i][3]);
            *(uint2*)(y2 + (size_t)(n0 + i) * 32 + (o4 >> 1)) = p;
        }
    }
}

// ---- bucket gather: register-staged counting-sort + per-node reg accum --
__global__ __launch_bounds__(GTHREADS) void bucket_gather(
        const unsigned* __restrict__ y2, const unsigned* __restrict__ pairs,
        const int* __restrict__ offs, const int* __restrict__ endc,
        const float* __restrict__ deg, const float* __restrict__ b,
        float* __restrict__ out, int N) {
    __shared__ unsigned list[CAP];           // sorted srcs, 8 KB
    __shared__ int cnt[BNODES], st[BNODES], sc[BNODES];
    int t = threadIdx.x;
    int bkt = blockIdx.x, base = bkt << BSHIFT;
    int start = offs[bkt], end = endc[bkt];  // endc = cursor after partition
    int lane = t & 63, w = t >> 6;           // 8 waves
    int g = lane >> 4, c = lane & 15;        // node sub-index / column quad
    float4 bv = ((const float4*)b)[c];
    int nchunk = (end - start + CAP - 1) / CAP;
    if (nchunk < 1) nchunk = 1;              // empty bucket: still write b

    for (int ci = 0; ci < nchunk; ++ci) {
        int e0 = start + ci * CAP;
        int cn = end - e0; if (cn > CAP) cn = CAP; if (cn < 0) cn = 0;
        if (t < BNODES) cnt[t] = 0;
        __syncthreads();
        unsigned pv[PERTHREAD];
        #pragma unroll
        for (int j = 0; j < PERTHREAD; ++j) {             // one coalesced pass
            int i = t + j * GTHREADS;
            pv[j] = (i < cn) ? pairs[e0 + i] : 0xFFFFFFFFu;
            if (i < cn) atomicAdd(&cnt[pv[j] >> 17], 1);  // hist from registers
        }
        __syncthreads();
        if (t < BNODES) sc[t] = cnt[t];
        __syncthreads();
        for (int off = 1; off < BNODES; off <<= 1) {      // inclusive scan
            int v = (t < BNODES && t >= off) ? sc[t - off] : 0;
            __syncthreads();
            if (t < BNODES) sc[t] += v;
            __syncthreads();
        }
        if (t < BNODES) { st[t] = sc[t] - cnt[t]; sc[t] = sc[t] - cnt[t]; }
        __syncthreads();
        #pragma unroll
        for (int j = 0; j < PERTHREAD; ++j) {             // scatter from registers
            if (pv[j] != 0xFFFFFFFFu) {
                int pos = atomicAdd(&sc[pv[j] >> 17], 1);
                list[pos] = pv[j] & 0x1FFFFu;             // src only
            }
        }
        __syncthreads();

        // gather: wave w owns nodes [w*16, w*16+16); 4 nodes per step via g
        for (int nl0 = w * 16; nl0 < w * 16 + 16; nl0 += 4) {
            int mynode = nl0 + g;
            int n = base + mynode;
            int s0 = st[mynode], e1 = s0 + cnt[mynode];
            float ax = 0.f, ay = 0.f, az = 0.f, aw = 0.f;
            for (int i = s0; i < e1; ++i) {               // group-divergent trip
                unsigned src = list[i];                   // broadcast within group
                uint2 u = *(const uint2*)(y2 + (size_t)src * 32 + c * 2);
                ax += __uint_as_float(u.x << 16);
                ay += __uint_as_float(u.x & 0xffff0000u);
                az += __uint_as_float(u.y << 16);
                aw += __uint_as_float(u.y & 0xffff0000u);
            }
            if (n < N) {
                float* op = out + (size_t)n * 64 + c * 4;
                if (nchunk == 1) {
                    float invd = 1.0f / deg[n];
                    float4 o4 = {ax * invd + bv.x, ay * invd + bv.y,
                                 az * invd + bv.z, aw * invd + bv.w};
                    *(float4*)op = o4;
                } else {                                  // rare multi-chunk path
                    float4 p = {0.f, 0.f, 0.f, 0.f};
                    if (ci > 0) p = *(const float4*)op;   // same thread wrote it
                    p.x += ax; p.y += ay; p.z += az; p.w += aw;
                    if (ci == nchunk - 1) {
                        float invd = 1.0f / deg[n];
                        p = {p.x * invd + bv.x, p.y * invd + bv.y,
                             p.z * invd + bv.z, p.w * invd + bv.w};
                    }
                    *(float4*)op = p;
                }
            }
        }
        __syncthreads();                                  // LDS reuse next chunk
    }
}

// ---- fallback: atomic scatter + LDS GEMM --------------------------------
__global__ __launch_bounds__(256) void scatter_kernel(
        const float* __restrict__ x, const unsigned* __restrict__ ewords,
        float* __restrict__ agg, int E) {
    __shared__ int sflag;
    int s = detect_stride_block(ewords, E, &sflag);
    int gid = blockIdx.x * blockDim.x + threadIdx.x;
    int e = gid >> 4, q = gid & 15;
    if (e >= E) return;
    int src = (int)ewords[(size_t)e * s];
    int dst = (int)ewords[((size_t)E + e) * s];
    const float4 v = *(const float4*)(x + (size_t)src * D + q * 4);
    float* p = agg + (size_t)dst * D + q * 4;
    unsafeAtomicAdd(p + 0, v.x);
    unsafeAtomicAdd(p + 1, v.y);
    unsafeAtomicAdd(p + 2, v.z);
    unsafeAtomicAdd(p + 3, v.w);
}

__global__ __launch_bounds__(256) void gemm_kernel(
        float* __restrict__ inout, const float* __restrict__ deg,
        const float* __restrict__ W, const float* __restrict__ b, int nNodes) {
    __shared__ float Wt[64 * 65];
    __shared__ float rows[4 * 64];
    int t = threadIdx.x;
    for (int i = t; i < 64 * 64; i += 256) {
        int o = i >> 6, k = i & 63;
        Wt[k * 65 + o] = W[i];
    }
    int base = blockIdx.x * 4;
    int nl = t >> 6, o = t & 63;
    int n = base + nl;
    if (n < nNodes) {
        float invd = 1.0f / deg[n];
        rows[nl * 64 + o] = inout[(size_t)n * 64 + o] * invd;
    }
    __syncthreads();
    if (n >= nNodes) return;
    float acc = b[o];
    #pragma unroll
    for (int k = 0; k < 64; ++k)
        acc += rows[nl * 64 + k] * Wt[k * 65 + o];
    inout[(size_t)n * 64 + o] = acc;
}

extern "C" void kernel_launch(void* const* d_in, const int* in_sizes, int n_in,
                              void* d_out, int out_size, void* d_ws, size_t ws_size,
                              hipStream_t stream) {
    const float*    x      = (const float*)d_in[0];
    const unsigned* ewords = (const unsigned*)d_in[1];
    const float*    deg    = (const float*)d_in[2];
    const float*    W      = (const float*)d_in[3];
    const float*    b      = (const float*)d_in[4];
    float*          out    = (float*)d_out;

    const int E = in_sizes[1] / 2;
    const int N = in_sizes[2];
    const int nb = (N + BNODES - 1) >> BSHIFT;         // 782 for N=100000

    // ws layout: bcnt[MAXB] | offs[MAXB] | cursor[MAXB] | pairs[E+N] | y2[N*32]
    char* ws = (char*)d_ws;
    size_t bcntB = MAXB * 4, offB = MAXB * 4, curB = MAXB * 4;
    size_t pairB = (((size_t)E + N) * 4 + 63) & ~63ull;
    size_t need  = bcntB + offB + curB + pairB + (size_t)N * 32 * 4;

    if (ws_size >= need && N < (1 << 17) && nb <= MAXB) {
        int*      bcnt   = (int*)ws;
        int*      offs   = (int*)(ws + bcntB);
        int*      cursor = (int*)(ws + bcntB + offB);
        unsigned* pairs  = (unsigned*)(ws + bcntB + offB + curB);
        unsigned* y2     = (unsigned*)(ws + bcntB + offB + curB + pairB);

        deg_bucket_hist<<<(N + 1023) / 1024, 256, 0, stream>>>(deg, bcnt, N, nb);
        bucket_scan<<<1, 256, 0, stream>>>(bcnt, offs, cursor, nb);
        partition_kernel<<<(E + 8191) / 8192, 256, 0, stream>>>(
            ewords, cursor, pairs, E, nb);
        xw_kernel<<<(N + 63) / 64, 256, 0, stream>>>(x, W, y2, N);
        bucket_gather<<<nb, GTHREADS, 0, stream>>>(
            y2, pairs, offs, cursor, deg, b, out, N);
    } else {
        hipMemsetAsync(d_out, 0, (size_t)out_size * sizeof(float), stream);
        long long sthreads = (long long)E * 16;
        int sblocks = (int)((sthreads + 255) / 256);
        scatter_kernel<<<sblocks, 256, 0, stream>>>(x, ewords, out, E);
        gemm_kernel<<<(N + 3) / 4, 256, 0, stream>>>(out, deg, W, b, N);
    }
}

// Round 9
// 147.469 us; speedup vs baseline: 3.7953x; 1.0961x over previous
//
#include <hip/hip_runtime.h>

// SAGEConv-mean: out[n,:] = (sum_{e: dst[e]==n} x[src[e],:]) / deg[n] @ W^T + b
// N=100000, E=1000000, D=64, fp32 in/out (no fp32 MFMA -> VALU GEMM).
//
// Round 9: top-5 is now all harness ws-poison (45us fills). Cut our own chain from
// 5 dispatches to 3:
//   - static 2048-slot bucket regions in pairs[] -> hist+scan kernels deleted
//     (cursor zeroed by an 8KB memsetAsync; overflow -> spill list, folded into
//     gather: provably empty for this input, correct for any input)
//   - partition fused with xw (independent workloads, LDS union, branch on
//     blockIdx): VALU-heavy GEMM overlaps memory/atomic-heavy partition
//   - gather: single-chunk counting-sort + per-node register accum + spill + /deg+b
// Fallback: atomic scatter + LDS GEMM (ws too small or N >= 2^17 or nb > MAXB).

#define D 64
#define BSHIFT 7                  // 128 nodes per bucket
#define BNODES (1 << BSHIFT)
#define CAP 2048                  // static slots per bucket (mean fill 1280)
#define GTHREADS 512
#define PERTHREAD (CAP / GTHREADS)   // 4
#define MAXB 2048                 // max buckets supported by partition LDS

// Per-block edge-dtype detect: int64 little-endian => odd 32-bit words are zero
// high-halves. 64 samples -> P(false int32 hit) ~ (1/N)^64 ~ 0.
__device__ inline int detect_stride_block(const unsigned* __restrict__ words,
                                          int E, int* sflag) {
    int t = threadIdx.x;
    if (t < 64) {
        unsigned v = (t < E) ? words[2 * t + 1] : 0u;
        int any = __any(v != 0u);
        if (t == 0) *sflag = any ? 1 : 2;   // word stride: 1=int32, 2=int64
    }
    __syncthreads();
    return *sflag;
}

__device__ inline unsigned pack_bf16(float a, float b) {   // two fp32 -> bf16x2, RNE
    unsigned ua = __float_as_uint(a), ub = __float_as_uint(b);
    ua += 0x7fffu + ((ua >> 16) & 1u);
    ub += 0x7fffu + ((ub >> 16) & 1u);
    return (ua >> 16) | (ub & 0xffff0000u);
}

// ---- fused partition (blocks [0,pblocks)) + xw GEMM (rest) --------------
// partition: 8192 edges/block, 2 sub-batches; LDS count -> block reservation in
//   static bucket region -> LDS running-cursor write; overflow -> spill list.
// xw: y = x @ W^T -> packed bf16 (VGPR-capped 4x4 register tile).
__global__ __launch_bounds__(256, 4) void partition_xw_kernel(
        const unsigned* __restrict__ ewords, int* __restrict__ cursor,
        unsigned* __restrict__ pairs, uint2* __restrict__ spill,
        int* __restrict__ spillCnt,
        const float* __restrict__ x, const float* __restrict__ W,
        unsigned* __restrict__ y2, int E, int N, int nb, int pblocks) {
    __shared__ __align__(16) char smem[34832];   // union: xw 34816B | part 16388B
    int t = threadIdx.x;

    if ((int)blockIdx.x < pblocks) {
        // ---------------- partition ----------------
        int* lhist = (int*)smem;
        int* lbase = lhist + MAXB;
        int* sflag = lbase + MAXB;
        int s = detect_stride_block(ewords, E, sflag);
        for (int sub = 0; sub < 2; ++sub) {
            int base = blockIdx.x * 8192 + sub * 4096;
            if (base >= E) break;                 // uniform across block
            for (int i = t; i < nb; i += 256) lhist[i] = 0;
            __syncthreads();
            unsigned pv[16]; int bk[16];
            #pragma unroll
            for (int k = 0; k < 16; ++k) {
                int e = base + k * 256 + t;
                bk[k] = -1;
                if (e < E) {
                    unsigned src = ewords[(size_t)e * s];
                    unsigned dst = ewords[((size_t)E + e) * s];
                    bk[k] = (int)(dst >> BSHIFT);
                    pv[k] = src | ((dst & (BNODES - 1)) << 17);
                    atomicAdd(&lhist[bk[k]], 1);
                }
            }
            __syncthreads();
            for (int hb = t; hb < nb; hb += 256) {
                int cc = lhist[hb];
                if (cc) lbase[hb] = atomicAdd(&cursor[hb], cc);
                lhist[hb] = 0;                    // reuse as running cursor
            }
            __syncthreads();
            #pragma unroll
            for (int k = 0; k < 16; ++k) {
                if (bk[k] >= 0) {
                    int lpos = lbase[bk[k]] + atomicAdd(&lhist[bk[k]], 1);
                    if (lpos < CAP) {
                        pairs[(size_t)bk[k] * CAP + lpos] = pv[k];
                    } else {                      // overflow (never for this input)
                        int si = atomicAdd(spillCnt, 1);
                        unsigned dst = ((unsigned)bk[k] << BSHIFT) | (pv[k] >> 17);
                        spill[si] = make_uint2(pv[k] & 0x1FFFFu, dst);
                    }
                }
            }
            __syncthreads();                      // protect lhist/lbase next sub
        }
    } else {
        // ---------------- xw: y = x @ W^T -> bf16 ----------------
        float* Wt = (float*)smem;                 // Wt[k*68+o]
        float* xs = Wt + 64 * 68;                 // xs[nl*68+k]
        for (int i = t; i < 64 * 64; i += 256) {
            int o = i >> 6, k = i & 63;
            Wt[k * 68 + o] = W[i];
        }
        int base = ((int)blockIdx.x - pblocks) * 64;
        int row = t >> 4, c4 = (t & 15) * 4;
        #pragma unroll
        for (int r = 0; r < 4; ++r) {
            int nl = row + r * 16;
            int n = base + nl;
            float4 v = {0.f, 0.f, 0.f, 0.f};
            if (n < N) v = *(const float4*)(x + (size_t)n * 64 + c4);
            *(float4*)&xs[nl * 68 + c4] = v;
        }
        __syncthreads();
        int o4 = (t & 15) * 4, nl4 = (t >> 4) * 4;
        float acc[4][4];
        #pragma unroll
        for (int i = 0; i < 4; ++i)
            #pragma unroll
            for (int j = 0; j < 4; ++j) acc[i][j] = 0.f;
        #pragma unroll 2
        for (int k0 = 0; k0 < 64; k0 += 4) {
            float a[4][4], wv[4][4];
            #pragma unroll
            for (int i = 0; i < 4; ++i)
                *(float4*)a[i] = *(const float4*)&xs[(nl4 + i) * 68 + k0];
            #pragma unroll
            for (int dk = 0; dk < 4; ++dk)
                *(float4*)wv[dk] = *(const float4*)&Wt[(k0 + dk) * 68 + o4];
            #pragma unroll
            for (int i = 0; i < 4; ++i)
                #pragma unroll
                for (int j = 0; j < 4; ++j)
                    acc[i][j] += a[i][0] * wv[0][j] + a[i][1] * wv[1][j]
                               + a[i][2] * wv[2][j] + a[i][3] * wv[3][j];
        }
        int n0 = base + nl4;
        #pragma unroll
        for (int i = 0; i < 4; ++i) {
            if (n0 + i < N) {
                uint2 p;
                p.x = pack_bf16(acc[i][0], acc[i][1]);
                p.y = pack_bf16(acc[i][2], acc[i][3]);
                *(uint2*)(y2 + (size_t)(n0 + i) * 32 + (o4 >> 1)) = p;
            }
        }
    }
}

// ---- bucket gather: register-staged counting-sort + per-node reg accum --
__global__ __launch_bounds__(GTHREADS) void bucket_gather(
        const unsigned* __restrict__ y2, const unsigned* __restrict__ pairs,
        const int* __restrict__ cursor, const uint2* __restrict__ spill,
        const int* __restrict__ spillCnt,
        const float* __restrict__ deg, const float* __restrict__ b,
        float* __restrict__ out, int N) {
    __shared__ unsigned list[CAP];           // sorted srcs, 8 KB
    __shared__ int cnt[BNODES], st[BNODES], sc[BNODES];
    int t = threadIdx.x;
    int bkt = blockIdx.x, base = bkt << BSHIFT;
    int total = cursor[bkt];
    int cn = total < CAP ? total : CAP;      // slots [0,cn) valid; rest spilled
    int lane = t & 63, w = t >> 6;           // 8 waves
    int g = lane >> 4, c = lane & 15;        // node sub-index / column quad
    float4 bv = ((const float4*)b)[c];

    if (t < BNODES) cnt[t] = 0;
    __syncthreads();
    unsigned pv[PERTHREAD];
    #pragma unroll
    for (int j = 0; j < PERTHREAD; ++j) {             // one coalesced pass
        int i = t + j * GTHREADS;
        pv[j] = (i < cn) ? pairs[(size_t)bkt * CAP + i] : 0xFFFFFFFFu;
        if (i < cn) atomicAdd(&cnt[pv[j] >> 17], 1);  // hist from registers
    }
    __syncthreads();
    if (t < BNODES) sc[t] = cnt[t];
    __syncthreads();
    for (int off = 1; off < BNODES; off <<= 1) {      // inclusive scan
        int v = (t < BNODES && t >= off) ? sc[t - off] : 0;
        __syncthreads();
        if (t < BNODES) sc[t] += v;
        __syncthreads();
    }
    if (t < BNODES) { st[t] = sc[t] - cnt[t]; sc[t] = sc[t] - cnt[t]; }
    __syncthreads();
    #pragma unroll
    for (int j = 0; j < PERTHREAD; ++j) {             // scatter from registers
        if (pv[j] != 0xFFFFFFFFu) {
            int pos = atomicAdd(&sc[pv[j] >> 17], 1);
            list[pos] = pv[j] & 0x1FFFFu;             // src only
        }
    }
    __syncthreads();

    int scnt = *spillCnt;                             // 0 in practice

    // gather: wave w owns nodes [w*16, w*16+16); 4 nodes per step via g
    for (int nl0 = w * 16; nl0 < w * 16 + 16; nl0 += 4) {
        int mynode = nl0 + g;
        int n = base + mynode;
        int s0 = st[mynode], e1 = s0 + cnt[mynode];
        float ax = 0.f, ay = 0.f, az = 0.f, aw = 0.f;
        for (int i = s0; i < e1; ++i) {               // group-divergent trip
            unsigned src = list[i];                   // broadcast within group
            uint2 u = *(const uint2*)(y2 + (size_t)src * 32 + c * 2);
            ax += __uint_as_float(u.x << 16);
            ay += __uint_as_float(u.x & 0xffff0000u);
            az += __uint_as_float(u.y << 16);
            aw += __uint_as_float(u.y & 0xffff0000u);
        }
        for (int i = 0; i < scnt; ++i) {              // overflow path (empty)
            uint2 e = spill[i];
            if ((int)e.y == n) {
                uint2 u = *(const uint2*)(y2 + (size_t)e.x * 32 + c * 2);
                ax += __uint_as_float(u.x << 16);
                ay += __uint_as_float(u.x & 0xffff0000u);
                az += __uint_as_float(u.y << 16);
                aw += __uint_as_float(u.y & 0xffff0000u);
            }
        }
        if (n < N) {
            float invd = 1.0f / deg[n];
            float4 o4 = {ax * invd + bv.x, ay * invd + bv.y,
                         az * invd + bv.z, aw * invd + bv.w};
            *(float4*)(out + (size_t)n * 64 + c * 4) = o4;
        }
    }
}

// ---- fallback: atomic scatter + LDS GEMM --------------------------------
__global__ __launch_bounds__(256) void scatter_kernel(
        const float* __restrict__ x, const unsigned* __restrict__ ewords,
        float* __restrict__ agg, int E) {
    __shared__ int sflag;
    int s = detect_stride_block(ewords, E, &sflag);
    int gid = blockIdx.x * blockDim.x + threadIdx.x;
    int e = gid >> 4, q = gid & 15;
    if (e >= E) return;
    int src = (int)ewords[(size_t)e * s];
    int dst = (int)ewords[((size_t)E + e) * s];
    const float4 v = *(const float4*)(x + (size_t)src * D + q * 4);
    float* p = agg + (size_t)dst * D + q * 4;
    unsafeAtomicAdd(p + 0, v.x);
    unsafeAtomicAdd(p + 1, v.y);
    unsafeAtomicAdd(p + 2, v.z);
    unsafeAtomicAdd(p + 3, v.w);
}

__global__ __launch_bounds__(256) void gemm_kernel(
        float* __restrict__ inout, const float* __restrict__ deg,
        const float* __restrict__ W, const float* __restrict__ b, int nNodes) {
    __shared__ float Wt[64 * 65];
    __shared__ float rows[4 * 64];
    int t = threadIdx.x;
    for (int i = t; i < 64 * 64; i += 256) {
        int o = i >> 6, k = i & 63;
        Wt[k * 65 + o] = W[i];
    }
    int base = blockIdx.x * 4;
    int nl = t >> 6, o = t & 63;
    int n = base + nl;
    if (n < nNodes) {
        float invd = 1.0f / deg[n];
        rows[nl * 64 + o] = inout[(size_t)n * 64 + o] * invd;
    }
    __syncthreads();
    if (n >= nNodes) return;
    float acc = b[o];
    #pragma unroll
    for (int k = 0; k < 64; ++k)
        acc += rows[nl * 64 + k] * Wt[k * 65 + o];
    inout[(size_t)n * 64 + o] = acc;
}

extern "C" void kernel_launch(void* const* d_in, const int* in_sizes, int n_in,
                              void* d_out, int out_size, void* d_ws, size_t ws_size,
                              hipStream_t stream) {
    const float*    x      = (const float*)d_in[0];
    const unsigned* ewords = (const unsigned*)d_in[1];
    const float*    deg    = (const float*)d_in[2];
    const float*    W      = (const float*)d_in[3];
    const float*    b      = (const float*)d_in[4];
    float*          out    = (float*)d_out;

    const int E = in_sizes[1] / 2;
    const int N = in_sizes[2];
    const int nb = (N + BNODES - 1) >> BSHIFT;         // 782 for N=100000

    // ws layout: cursor[MAXB] + spillCnt | pairs[nb*CAP] | spill[E] | y2[N*32]
    char* ws = (char*)d_ws;
    size_t curB  = (MAXB + 16) * 4;
    size_t pairB = ((size_t)nb * CAP * 4 + 63) & ~63ull;
    size_t spB   = ((size_t)E * 8 + 63) & ~63ull;
    size_t need  = curB + pairB + spB + (size_t)N * 32 * 4;

    if (ws_size >= need && N < (1 << 17) && nb <= MAXB) {
        int*      cursor   = (int*)ws;
        int*      spillCnt = cursor + MAXB;
        unsigned* pairs    = (unsigned*)(ws + curB);
        uint2*    spill    = (uint2*)(ws + curB + pairB);
        unsigned* y2       = (unsigned*)(ws + curB + pairB + spB);

        hipMemsetAsync(cursor, 0, curB, stream);       // 8KB: cursors + spillCnt

        int pblocks  = (E + 8191) / 8192;
        int xwblocks = (N + 63) / 64;
        partition_xw_kernel<<<pblocks + xwblocks, 256, 0, stream>>>(
            ewords, cursor, pairs, spill, spillCnt, x, W, y2, E, N, nb, pblocks);

        bucket_gather<<<nb, GTHREADS, 0, stream>>>(
            y2, pairs, cursor, spill, spillCnt, deg, b, out, N);
    } else {
        hipMemsetAsync(d_out, 0, (size_t)out_size * sizeof(float), stream);
        long long sthreads = (long long)E * 16;
        int sblocks = (int)((sthreads + 255) / 256);
        scatter_kernel<<<sblocks, 256, 0, stream>>>(x, ewords, out, E);
        gemm_kernel<<<(N + 3) / 4, 256, 0, stream>>>(out, deg, W, b, N);
    }
}

// Round 10
// 140.842 us; speedup vs baseline: 3.9738x; 1.0471x over previous
//
#include <hip/hip_runtime.h>

// SAGEConv-mean: out[n,:] = (sum_{e: dst[e]==n} x[src[e],:]) / deg[n] @ W^T + b
// N=100000, E=1000000, D=64, fp32 in/out (no fp32 MFMA -> VALU GEMM).
//
// Round 10: harness ws-poison (45us) + restores now top the profile; remaining
// controllables are the two fused kernels. Changes vs r9:
//   - partition_xw at 512 threads: partition does one 8192-edge pass (16/thread,
//     single bucket reservation; half the critical path, half the global reserve
//     atomics); xw does 128-node tiles (Wt + xs = 52KB LDS union, 3 blocks/CU).
//   - bucket_gather: 2-edge manual unroll with dual accumulator sets -> 2x loads
//     in flight, broken add dependency chain.
// Chain: memset(8KB cursors) -> partition_xw -> bucket_gather  (3 dispatches).
// Fallback: atomic scatter + LDS GEMM (ws too small or N >= 2^17 or nb > MAXB).

#define D 64
#define BSHIFT 7                  // 128 nodes per bucket
#define BNODES (1 << BSHIFT)
#define CAP 2048                  // static slots per bucket (mean fill 1280)
#define GTHREADS 512
#define PERTHREAD (CAP / GTHREADS)   // 4
#define PXW_THREADS 512
#define MAXB 2048                 // max buckets supported by partition LDS

// Per-block edge-dtype detect: int64 little-endian => odd 32-bit words are zero
// high-halves. 64 samples -> P(false int32 hit) ~ (1/N)^64 ~ 0.
__device__ inline int detect_stride_block(const unsigned* __restrict__ words,
                                          int E, int* sflag) {
    int t = threadIdx.x;
    if (t < 64) {
        unsigned v = (t < E) ? words[2 * t + 1] : 0u;
        int any = __any(v != 0u);
        if (t == 0) *sflag = any ? 1 : 2;   // word stride: 1=int32, 2=int64
    }
    __syncthreads();
    return *sflag;
}

__device__ inline unsigned pack_bf16(float a, float b) {   // two fp32 -> bf16x2, RNE
    unsigned ua = __float_as_uint(a), ub = __float_as_uint(b);
    ua += 0x7fffu + ((ua >> 16) & 1u);
    ub += 0x7fffu + ((ub >> 16) & 1u);
    return (ua >> 16) | (ub & 0xffff0000u);
}

// ---- fused partition (blocks [0,pblocks)) + xw GEMM (rest), 512 thr -----
__global__ __launch_bounds__(PXW_THREADS, 4) void partition_xw_kernel(
        const unsigned* __restrict__ ewords, int* __restrict__ cursor,
        unsigned* __restrict__ pairs, uint2* __restrict__ spill,
        int* __restrict__ spillCnt,
        const float* __restrict__ x, const float* __restrict__ W,
        unsigned* __restrict__ y2, int E, int N, int nb, int pblocks) {
    __shared__ __align__(16) char smem[52240];   // xw 52224B | part 16388B
    int t = threadIdx.x;

    if ((int)blockIdx.x < pblocks) {
        // ---------------- partition: 8192 edges, one pass ----------------
        int* lhist = (int*)smem;
        int* lbase = lhist + MAXB;
        int* sflag = lbase + MAXB;
        int s = detect_stride_block(ewords, E, sflag);
        int base = blockIdx.x * 8192;
        for (int i = t; i < nb; i += PXW_THREADS) lhist[i] = 0;
        __syncthreads();
        unsigned pv[16]; int bk[16];
        #pragma unroll
        for (int k = 0; k < 16; ++k) {
            int e = base + k * PXW_THREADS + t;
            bk[k] = -1;
            if (e < E) {
                unsigned src = ewords[(size_t)e * s];
                unsigned dst = ewords[((size_t)E + e) * s];
                bk[k] = (int)(dst >> BSHIFT);
                pv[k] = src | ((dst & (BNODES - 1)) << 17);
                atomicAdd(&lhist[bk[k]], 1);
            }
        }
        __syncthreads();
        for (int hb = t; hb < nb; hb += PXW_THREADS) {
            int cc = lhist[hb];
            if (cc) lbase[hb] = atomicAdd(&cursor[hb], cc);
            lhist[hb] = 0;                    // reuse as running cursor
        }
        __syncthreads();
        #pragma unroll
        for (int k = 0; k < 16; ++k) {
            if (bk[k] >= 0) {
                int lpos = lbase[bk[k]] + atomicAdd(&lhist[bk[k]], 1);
                if (lpos < CAP) {
                    pairs[(size_t)bk[k] * CAP + lpos] = pv[k];
                } else {                      // overflow (never for this input)
                    int si = atomicAdd(spillCnt, 1);
                    unsigned dst = ((unsigned)bk[k] << BSHIFT) | (pv[k] >> 17);
                    spill[si] = make_uint2(pv[k] & 0x1FFFFu, dst);
                }
            }
        }
    } else {
        // ---------------- xw: 128-node tile, y = x @ W^T -> bf16 ---------
        float* Wt = (float*)smem;                 // Wt[k*68+o], 17408B
        float* xs = Wt + 64 * 68;                 // xs[nl*68+k], 34816B
        for (int i = t; i < 64 * 64; i += PXW_THREADS) {
            int o = i >> 6, k = i & 63;
            Wt[k * 68 + o] = W[i];
        }
        int base = ((int)blockIdx.x - pblocks) * 128;
        int row = t >> 4, c4 = (t & 15) * 4;      // row 0..31
        #pragma unroll
        for (int r = 0; r < 4; ++r) {
            int nl = row + r * 32;
            int n = base + nl;
            float4 v = {0.f, 0.f, 0.f, 0.f};
            if (n < N) v = *(const float4*)(x + (size_t)n * 64 + c4);
            *(float4*)&xs[nl * 68 + c4] = v;
        }
        __syncthreads();
        int o4 = (t & 15) * 4, nl4 = (t >> 4) * 4;   // nl4 0..124
        float acc[4][4];
        #pragma unroll
        for (int i = 0; i < 4; ++i)
            #pragma unroll
            for (int j = 0; j < 4; ++j) acc[i][j] = 0.f;
        #pragma unroll 2
        for (int k0 = 0; k0 < 64; k0 += 4) {
            float a[4][4], wv[4][4];
            #pragma unroll
            for (int i = 0; i < 4; ++i)
                *(float4*)a[i] = *(const float4*)&xs[(nl4 + i) * 68 + k0];
            #pragma unroll
            for (int dk = 0; dk < 4; ++dk)
                *(float4*)wv[dk] = *(const float4*)&Wt[(k0 + dk) * 68 + o4];
            #pragma unroll
            for (int i = 0; i < 4; ++i)
                #pragma unroll
                for (int j = 0; j < 4; ++j)
                    acc[i][j] += a[i][0] * wv[0][j] + a[i][1] * wv[1][j]
                               + a[i][2] * wv[2][j] + a[i][3] * wv[3][j];
        }
        int n0 = base + nl4;
        #pragma unroll
        for (int i = 0; i < 4; ++i) {
            if (n0 + i < N) {
                uint2 p;
                p.x = pack_bf16(acc[i][0], acc[i][1]);
                p.y = pack_bf16(acc[i][2], acc[i][3]);
                *(uint2*)(y2 + (size_t)(n0 + i) * 32 + (o4 >> 1)) = p;
            }
        }
    }
}

// ---- bucket gather: counting-sort + dual-accumulator register gather ----
__global__ __launch_bounds__(GTHREADS) void bucket_gather(
        const unsigned* __restrict__ y2, const unsigned* __restrict__ pairs,
        const int* __restrict__ cursor, const uint2* __restrict__ spill,
        const int* __restrict__ spillCnt,
        const float* __restrict__ deg, const float* __restrict__ b,
        float* __restrict__ out, int N) {
    __shared__ unsigned list[CAP];           // sorted srcs, 8 KB
    __shared__ int cnt[BNODES], st[BNODES], sc[BNODES];
    int t = threadIdx.x;
    int bkt = blockIdx.x, base = bkt << BSHIFT;
    int total = cursor[bkt];
    int cn = total < CAP ? total : CAP;      // slots [0,cn) valid; rest spilled
    int lane = t & 63, w = t >> 6;           // 8 waves
    int g = lane >> 4, c = lane & 15;        // node sub-index / column quad
    float4 bv = ((const float4*)b)[c];

    if (t < BNODES) cnt[t] = 0;
    __syncthreads();
    unsigned pv[PERTHREAD];
    #pragma unroll
    for (int j = 0; j < PERTHREAD; ++j) {             // one coalesced pass
        int i = t + j * GTHREADS;
        pv[j] = (i < cn) ? pairs[(size_t)bkt * CAP + i] : 0xFFFFFFFFu;
        if (i < cn) atomicAdd(&cnt[pv[j] >> 17], 1);  // hist from registers
    }
    __syncthreads();
    if (t < BNODES) sc[t] = cnt[t];
    __syncthreads();
    for (int off = 1; off < BNODES; off <<= 1) {      // inclusive scan
        int v = (t < BNODES && t >= off) ? sc[t - off] : 0;
        __syncthreads();
        if (t < BNODES) sc[t] += v;
        __syncthreads();
    }
    if (t < BNODES) { st[t] = sc[t] - cnt[t]; sc[t] = sc[t] - cnt[t]; }
    __syncthreads();
    #pragma unroll
    for (int j = 0; j < PERTHREAD; ++j) {             // scatter from registers
        if (pv[j] != 0xFFFFFFFFu) {
            int pos = atomicAdd(&sc[pv[j] >> 17], 1);
            list[pos] = pv[j] & 0x1FFFFu;             // src only
        }
    }
    __syncthreads();

    int scnt = *spillCnt;                             // 0 in practice

    // gather: wave w owns nodes [w*16, w*16+16); 4 nodes per step via g
    for (int nl0 = w * 16; nl0 < w * 16 + 16; nl0 += 4) {
        int mynode = nl0 + g;
        int n = base + mynode;
        int s0 = st[mynode], e1 = s0 + cnt[mynode];
        float ax = 0.f, ay = 0.f, az = 0.f, aw = 0.f;   // even edges
        float bx = 0.f, by = 0.f, bz = 0.f, bw = 0.f;   // odd edges
        int i = s0;
        for (; i + 1 < e1; i += 2) {                  // 2 loads in flight
            unsigned s0v = list[i], s1v = list[i + 1];
            uint2 u0 = *(const uint2*)(y2 + (size_t)s0v * 32 + c * 2);
            uint2 u1 = *(const uint2*)(y2 + (size_t)s1v * 32 + c * 2);
            ax += __uint_as_float(u0.x << 16);
            ay += __uint_as_float(u0.x & 0xffff0000u);
            az += __uint_as_float(u0.y << 16);
            aw += __uint_as_float(u0.y & 0xffff0000u);
            bx += __uint_as_float(u1.x << 16);
            by += __uint_as_float(u1.x & 0xffff0000u);
            bz += __uint_as_float(u1.y << 16);
            bw += __uint_as_float(u1.y & 0xffff0000u);
        }
        if (i < e1) {
            unsigned sv = list[i];
            uint2 u = *(const uint2*)(y2 + (size_t)sv * 32 + c * 2);
            ax += __uint_as_float(u.x << 16);
            ay += __uint_as_float(u.x & 0xffff0000u);
            az += __uint_as_float(u.y << 16);
            aw += __uint_as_float(u.y & 0xffff0000u);
        }
        ax += bx; ay += by; az += bz; aw += bw;
        for (int k = 0; k < scnt; ++k) {              // overflow path (empty)
            uint2 e = spill[k];
            if ((int)e.y == n) {
                uint2 u = *(const uint2*)(y2 + (size_t)e.x * 32 + c * 2);
                ax += __uint_as_float(u.x << 16);
                ay += __uint_as_float(u.x & 0xffff0000u);
                az += __uint_as_float(u.y << 16);
                aw += __uint_as_float(u.y & 0xffff0000u);
            }
        }
        if (n < N) {
            float invd = 1.0f / deg[n];
            float4 o4 = {ax * invd + bv.x, ay * invd + bv.y,
                         az * invd + bv.z, aw * invd + bv.w};
            *(float4*)(out + (size_t)n * 64 + c * 4) = o4;
        }
    }
}

// ---- fallback: atomic scatter + LDS GEMM --------------------------------
__global__ __launch_bounds__(256) void scatter_kernel(
        const float* __restrict__ x, const unsigned* __restrict__ ewords,
        float* __restrict__ agg, int E) {
    __shared__ int sflag;
    int s = detect_stride_block(ewords, E, &sflag);
    int gid = blockIdx.x * blockDim.x + threadIdx.x;
    int e = gid >> 4, q = gid & 15;
    if (e >= E) return;
    int src = (int)ewords[(size_t)e * s];
    int dst = (int)ewords[((size_t)E + e) * s];
    const float4 v = *(const float4*)(x + (size_t)src * D + q * 4);
    float* p = agg + (size_t)dst * D + q * 4;
    unsafeAtomicAdd(p + 0, v.x);
    unsafeAtomicAdd(p + 1, v.y);
    unsafeAtomicAdd(p + 2, v.z);
    unsafeAtomicAdd(p + 3, v.w);
}

__global__ __launch_bounds__(256) void gemm_kernel(
        float* __restrict__ inout, const float* __restrict__ deg,
        const float* __restrict__ W, const float* __restrict__ b, int nNodes) {
    __shared__ float Wt[64 * 65];
    __shared__ float rows[4 * 64];
    int t = threadIdx.x;
    for (int i = t; i < 64 * 64; i += 256) {
        int o = i >> 6, k = i & 63;
        Wt[k * 65 + o] = W[i];
    }
    int base = blockIdx.x * 4;
    int nl = t >> 6, o = t & 63;
    int n = base + nl;
    if (n < nNodes) {
        float invd = 1.0f / deg[n];
        rows[nl * 64 + o] = inout[(size_t)n * 64 + o] * invd;
    }
    __syncthreads();
    if (n >= nNodes) return;
    float acc = b[o];
    #pragma unroll
    for (int k = 0; k < 64; ++k)
        acc += rows[nl * 64 + k] * Wt[k * 65 + o];
    inout[(size_t)n * 64 + o] = acc;
}

extern "C" void kernel_launch(void* const* d_in, const int* in_sizes, int n_in,
                              void* d_out, int out_size, void* d_ws, size_t ws_size,
                              hipStream_t stream) {
    const float*    x      = (const float*)d_in[0];
    const unsigned* ewords = (const unsigned*)d_in[1];
    const float*    deg    = (const float*)d_in[2];
    const float*    W      = (const float*)d_in[3];
    const float*    b      = (const float*)d_in[4];
    float*          out    = (float*)d_out;

    const int E = in_sizes[1] / 2;
    const int N = in_sizes[2];
    const int nb = (N + BNODES - 1) >> BSHIFT;         // 782 for N=100000

    // ws layout: cursor[MAXB] + spillCnt | pairs[nb*CAP] | spill[E] | y2[N*32]
    char* ws = (char*)d_ws;
    size_t curB  = (MAXB + 16) * 4;
    size_t pairB = ((size_t)nb * CAP * 4 + 63) & ~63ull;
    size_t spB   = ((size_t)E * 8 + 63) & ~63ull;
    size_t need  = curB + pairB + spB + (size_t)N * 32 * 4;

    if (ws_size >= need && N < (1 << 17) && nb <= MAXB) {
        int*      cursor   = (int*)ws;
        int*      spillCnt = cursor + MAXB;
        unsigned* pairs    = (unsigned*)(ws + curB);
        uint2*    spill    = (uint2*)(ws + curB + pairB);
        unsigned* y2       = (unsigned*)(ws + curB + pairB + spB);

        hipMemsetAsync(cursor, 0, curB, stream);       // 8KB: cursors + spillCnt

        int pblocks  = (E + 8191) / 8192;
        int xwblocks = (N + 127) / 128;
        partition_xw_kernel<<<pblocks + xwblocks, PXW_THREADS, 0, stream>>>(
            ewords, cursor, pairs, spill, spillCnt, x, W, y2, E, N, nb, pblocks);

        bucket_gather<<<nb, GTHREADS, 0, stream>>>(
            y2, pairs, cursor, spill, spillCnt, deg, b, out, N);
    } else {
        hipMemsetAsync(d_out, 0, (size_t)out_size * sizeof(float), stream);
        long long sthreads = (long long)E * 16;
        int sblocks = (int)((sthreads + 255) / 256);
        scatter_kernel<<<sblocks, 256, 0, stream>>>(x, ewords, out, E);
        gemm_kernel<<<(N + 3) / 4, 256, 0, stream>>>(out, deg, W, b, N);
    }
}